// Round 1
// baseline (274.643 us; speedup 1.0000x reference)
//
#include <hip/hip_runtime.h>
#include <hip/hip_bf16.h>
#include <math.h>

typedef __bf16 bf16_t;
typedef bf16_t bf16x8 __attribute__((ext_vector_type(8)));
typedef bf16_t bf16x4 __attribute__((ext_vector_type(4)));
typedef float f32x4 __attribute__((ext_vector_type(4)));

#define DEV_INLINE __device__ __forceinline__

constexpr int B_ = 4, T_ = 2048, DM = 1024, NH = 8, RK = 64;
constexpr int BT = B_ * T_;        // 8192
constexpr int QC = NH * RK;        // 512

// ---------------------------------------------------------------- cast f32->bf16
__global__ void cast_f32_bf16(const float* __restrict__ in, bf16_t* __restrict__ out, int n) {
  int i = (blockIdx.x * blockDim.x + threadIdx.x) * 4;
  if (i >= n) return;
  const float4 v = *reinterpret_cast<const float4*>(in + i);
  bf16x4 o;
  o[0] = (bf16_t)v.x; o[1] = (bf16_t)v.y; o[2] = (bf16_t)v.z; o[3] = (bf16_t)v.w;
  *reinterpret_cast<bf16x4*>(out + i) = o;
}

// ---------------------------------------------------------------- Wq_eff[(h*64+r), m] = sum_d Wk_up[(h*256+d)*64+r] * Wq[(h*256+d)*1024+m]
__global__ void build_wq_eff(const float* __restrict__ Wku, const float* __restrict__ Wq,
                             bf16_t* __restrict__ out) {
  const int m = blockIdx.x * 256 + threadIdx.x;   // [0,1024)
  const int h = blockIdx.y;                       // [0,8)
  const int r0 = blockIdx.z * 8;                  // [0,64) step 8
  float s[8] = {};
  const float* wk = Wku + (size_t)h * 256 * 64 + r0;
  const float* wq = Wq + (size_t)h * 256 * 1024 + m;
  for (int d = 0; d < 256; ++d) {
    float qv = wq[(size_t)d * 1024];
#pragma unroll
    for (int j = 0; j < 8; ++j) s[j] += wk[d * 64 + j] * qv;
  }
#pragma unroll
  for (int j = 0; j < 8; ++j) out[(size_t)(h * 64 + r0 + j) * 1024 + m] = (bf16_t)s[j];
}

// ---------------------------------------------------------------- W_eff[m*512 + h*64 + r] = sum_d Wo[m*2048 + h*256 + d] * Wv_up[(h*256+d)*64 + r]
__global__ void build_w_eff(const float* __restrict__ Wo, const float* __restrict__ Wvu,
                            bf16_t* __restrict__ out) {
  const int m = blockIdx.x;                        // [0,1024)
  const int h = blockIdx.y * 4 + (threadIdx.x >> 6);
  const int r = threadIdx.x & 63;
  float s = 0.f;
  const float* wo = Wo + (size_t)m * 2048 + h * 256;
  const float* wv = Wvu + (size_t)h * 256 * 64 + r;
  for (int d = 0; d < 256; ++d) s += wo[d] * wv[d * 64];
  out[(size_t)m * 512 + h * 64 + r] = (bf16_t)s;
}

// ---------------------------------------------------------------- transpose c: cT[b][r][t] = c[b][t][r]
__global__ void transpose_c(const bf16_t* __restrict__ c, bf16_t* __restrict__ cT) {
  __shared__ bf16_t tile[64][65];
  const int b = blockIdx.y;
  const int t0 = blockIdx.x * 64;
  const int tx = threadIdx.x & 63;
  const int ty = threadIdx.x >> 6;   // 0..3
#pragma unroll
  for (int i = 0; i < 16; ++i) {
    int t = ty * 16 + i;
    tile[t][tx] = c[((size_t)b * T_ + t0 + t) * RK + tx];
  }
  __syncthreads();
#pragma unroll
  for (int i = 0; i < 16; ++i) {
    int r = ty * 16 + i;
    cT[((size_t)b * RK + r) * T_ + t0 + tx] = tile[tx][r];
  }
}

// ---------------------------------------------------------------- GEMM C[M,N] = A[M,K] * B[N,K]^T (bf16 in, f32 acc)
DEV_INLINE void storeC(float* p, float v) { *p = v; }
DEV_INLINE void storeC(bf16_t* p, float v) { *p = (bf16_t)v; }

DEV_INLINE void async_load16(const void* g, void* l) {
  __builtin_amdgcn_global_load_lds((__attribute__((address_space(1))) void*)g,
                                   (__attribute__((address_space(3))) void*)l, 16, 0, 0);
}

template <typename OutT>
__global__ __launch_bounds__(256) void gemm_bt(const bf16_t* __restrict__ A,
                                               const bf16_t* __restrict__ Bm,
                                               OutT* __restrict__ C, int M, int N, int K) {
  __shared__ bf16_t lA[128 * 32];
  __shared__ bf16_t lB[128 * 32];
  const int tid = threadIdx.x;
  const int lane = tid & 63;
  const int w = tid >> 6;
  const int lo = lane & 15, hi = lane >> 4;
  const int wr = w >> 1, wc = w & 1;
  const size_t row0 = (size_t)blockIdx.x * 128;
  const size_t col0 = (size_t)blockIdx.y * 128;
  const int w64 = w * 64;
  f32x4 acc[4][4] = {};

  for (int k0 = 0; k0 < K; k0 += 32) {
    __syncthreads();
#pragma unroll
    for (int j = 0; j < 2; ++j) {
      const int chunk = j * 256 + w64 + lane;
      const int r = chunk >> 2;
      const int kk = (chunk & 3) * 8;
      const bf16_t* gA = A + (row0 + r) * K + (k0 + kk);
      async_load16(gA, &lA[(size_t)(j * 256 + w64) * 8]);
      size_t rB = col0 + r;
      if (rB >= (size_t)N) rB = N - 1;
      const bf16_t* gB = Bm + rB * K + (k0 + kk);
      async_load16(gB, &lB[(size_t)(j * 256 + w64) * 8]);
    }
    __syncthreads();
    const bf16x8* pA = reinterpret_cast<const bf16x8*>(lA);
    const bf16x8* pB = reinterpret_cast<const bf16x8*>(lB);
    bf16x8 af[4], bfr[4];
#pragma unroll
    for (int m = 0; m < 4; ++m) af[m] = pA[(wr * 64 + m * 16 + lo) * 4 + hi];
#pragma unroll
    for (int n = 0; n < 4; ++n) bfr[n] = pB[(wc * 64 + n * 16 + lo) * 4 + hi];
#pragma unroll
    for (int m = 0; m < 4; ++m)
#pragma unroll
      for (int n = 0; n < 4; ++n)
        acc[m][n] = __builtin_amdgcn_mfma_f32_16x16x32_bf16(af[m], bfr[n], acc[m][n], 0, 0, 0);
  }
#pragma unroll
  for (int m = 0; m < 4; ++m)
#pragma unroll
    for (int n = 0; n < 4; ++n)
#pragma unroll
      for (int q = 0; q < 4; ++q) {
        const size_t row = row0 + wr * 64 + m * 16 + hi * 4 + q;
        const size_t col = col0 + wc * 64 + n * 16 + lo;
        if ((int)col < N) storeC(&C[row * N + col], acc[m][n][q]);
      }
}

// ---------------------------------------------------------------- flash attention (head_dim 64 both sides, K=V=c)
// Qt [BT, 512] (col = h*64+r), c [BT, 64], cT [B][64][T], U [BT, 512]
__global__ __launch_bounds__(256) void attn_kernel(const bf16_t* __restrict__ Qt,
                                                   const bf16_t* __restrict__ Cl,
                                                   const bf16_t* __restrict__ CT,
                                                   bf16_t* __restrict__ U) {
  __shared__ bf16_t Pl[4][2][16][40];
  const int tid = threadIdx.x;
  const int w = tid >> 6, lane = tid & 63;
  const int lo = lane & 15, hi = lane >> 4;
  const int b = blockIdx.z, h = blockIdx.y;
  const int q0 = blockIdx.x * 128;
  const size_t qbase = (size_t)b * T_ + q0 + w * 32;

  const bf16_t* cbase = Cl + (size_t)b * T_ * RK;
  const bf16_t* ctbase = CT + (size_t)b * RK * T_;

  // Q fragments: qf[rowset][kchunk]
  bf16x8 qf[2][2];
#pragma unroll
  for (int rs = 0; rs < 2; ++rs)
#pragma unroll
    for (int c0 = 0; c0 < 2; ++c0)
      qf[rs][c0] = *reinterpret_cast<const bf16x8*>(
          Qt + (qbase + rs * 16 + lo) * QC + h * RK + c0 * 32 + hi * 8);

  f32x4 acc[2][4] = {};
  float m_r[2][4], l_r[2][4];
#pragma unroll
  for (int rs = 0; rs < 2; ++rs)
#pragma unroll
    for (int q = 0; q < 4; ++q) { m_r[rs][q] = -INFINITY; l_r[rs][q] = 0.f; }

  for (int kv0 = 0; kv0 < T_; kv0 += 32) {
    // ---- QK^T for both rowsets (B-fragments shared)
    bf16x8 kf[2][2];
#pragma unroll
    for (int n = 0; n < 2; ++n)
#pragma unroll
      for (int c0 = 0; c0 < 2; ++c0)
        kf[n][c0] = *reinterpret_cast<const bf16x8*>(
            cbase + (size_t)(kv0 + n * 16 + lo) * RK + c0 * 32 + hi * 8);

    f32x4 s[2][2] = {};
#pragma unroll
    for (int rs = 0; rs < 2; ++rs)
#pragma unroll
      for (int n = 0; n < 2; ++n)
#pragma unroll
        for (int c0 = 0; c0 < 2; ++c0)
          s[rs][n] = __builtin_amdgcn_mfma_f32_16x16x32_bf16(qf[rs][c0], kf[n][c0], s[rs][n], 0, 0, 0);

    // ---- online softmax (scale 1/sqrt(256) = 1/16)
    float ps[2][2][4];
#pragma unroll
    for (int rs = 0; rs < 2; ++rs) {
      float mx[4];
#pragma unroll
      for (int q = 0; q < 4; ++q) {
        s[rs][0][q] *= 0.0625f;
        s[rs][1][q] *= 0.0625f;
        mx[q] = fmaxf(s[rs][0][q], s[rs][1][q]);
      }
#pragma unroll
      for (int msk = 1; msk < 16; msk <<= 1)
#pragma unroll
        for (int q = 0; q < 4; ++q) mx[q] = fmaxf(mx[q], __shfl_xor(mx[q], msk));
      float al[4], rsum[4];
#pragma unroll
      for (int q = 0; q < 4; ++q) {
        float mn = fmaxf(m_r[rs][q], mx[q]);
        al[q] = __expf(m_r[rs][q] - mn);
        m_r[rs][q] = mn;
        ps[rs][0][q] = __expf(s[rs][0][q] - mn);
        ps[rs][1][q] = __expf(s[rs][1][q] - mn);
        rsum[q] = ps[rs][0][q] + ps[rs][1][q];
      }
#pragma unroll
      for (int msk = 1; msk < 16; msk <<= 1)
#pragma unroll
        for (int q = 0; q < 4; ++q) rsum[q] += __shfl_xor(rsum[q], msk);
#pragma unroll
      for (int q = 0; q < 4; ++q) l_r[rs][q] = l_r[rs][q] * al[q] + rsum[q];
#pragma unroll
      for (int n = 0; n < 4; ++n)
#pragma unroll
        for (int q = 0; q < 4; ++q) acc[rs][n][q] *= al[q];
    }

    // ---- P transpose through per-wave LDS (no cross-wave sharing -> no barrier)
    asm volatile("s_waitcnt lgkmcnt(0)" ::: "memory");  // prev iter's pa reads done
#pragma unroll
    for (int rs = 0; rs < 2; ++rs)
#pragma unroll
      for (int n = 0; n < 2; ++n)
#pragma unroll
        for (int q = 0; q < 4; ++q)
          Pl[w][rs][hi * 4 + q][n * 16 + lo] = (bf16_t)ps[rs][n][q];
    asm volatile("s_waitcnt lgkmcnt(0)" ::: "memory");  // P writes visible wave-wide
    __builtin_amdgcn_sched_barrier(0);

    // ---- PV: U += P * c_tile  (B-fragments from pre-transposed cT, shared across rowsets)
    bf16x8 vf[4];
#pragma unroll
    for (int n = 0; n < 4; ++n)
      vf[n] = *reinterpret_cast<const bf16x8*>(
          ctbase + (size_t)(n * 16 + lo) * T_ + kv0 + hi * 8);
    bf16x8 pa[2];
#pragma unroll
    for (int rs = 0; rs < 2; ++rs)
      pa[rs] = *reinterpret_cast<const bf16x8*>(&Pl[w][rs][lo][hi * 8]);
#pragma unroll
    for (int rs = 0; rs < 2; ++rs)
#pragma unroll
      for (int n = 0; n < 4; ++n)
        acc[rs][n] = __builtin_amdgcn_mfma_f32_16x16x32_bf16(pa[rs], vf[n], acc[rs][n], 0, 0, 0);
  }

  // ---- epilogue
#pragma unroll
  for (int rs = 0; rs < 2; ++rs)
#pragma unroll
    for (int q = 0; q < 4; ++q) {
      float inv = 1.0f / l_r[rs][q];
#pragma unroll
      for (int n = 0; n < 4; ++n)
        U[(qbase + rs * 16 + hi * 4 + q) * QC + h * RK + n * 16 + lo] =
            (bf16_t)(acc[rs][n][q] * inv);
    }
}

// ---------------------------------------------------------------- launch
extern "C" void kernel_launch(void* const* d_in, const int* in_sizes, int n_in,
                              void* d_out, int out_size, void* d_ws, size_t ws_size,
                              hipStream_t stream) {
  const float* x   = (const float*)d_in[0];
  const float* Wq  = (const float*)d_in[1];
  const float* Wkd = (const float*)d_in[2];
  const float* Wku = (const float*)d_in[3];
  const float* Wvu = (const float*)d_in[4];
  const float* Wo  = (const float*)d_in[5];
  float* out = (float*)d_out;

  char* ws = (char*)d_ws;
  bf16_t* xb   = (bf16_t*)(ws + 0);          // 8192*1024 bf16 = 16 MiB
  bf16_t* cb   = (bf16_t*)(ws + 16777216);   // 8192*64          1 MiB
  bf16_t* qtb  = (bf16_t*)(ws + 17825792);   // 8192*512         8 MiB
  bf16_t* Ub   = (bf16_t*)(ws + 26214400);   // 8192*512         8 MiB
  bf16_t* Wqe  = (bf16_t*)(ws + 34603008);   // 512*1024         1 MiB
  bf16_t* Wfe  = (bf16_t*)(ws + 35651584);   // 1024*512         1 MiB
  bf16_t* Wkdb = (bf16_t*)(ws + 36700160);   // 64*1024          128 KiB
  bf16_t* cTb  = (bf16_t*)(ws + 36831232);   // 4*64*2048        1 MiB

  cast_f32_bf16<<<8192, 256, 0, stream>>>(x, xb, BT * DM);
  cast_f32_bf16<<<64, 256, 0, stream>>>(Wkd, Wkdb, RK * DM);
  build_wq_eff<<<dim3(4, 8, 8), 256, 0, stream>>>(Wku, Wq, Wqe);
  build_w_eff<<<dim3(1024, 2), 256, 0, stream>>>(Wo, Wvu, Wfe);

  // c = x @ Wkv_down^T   [8192, 64]
  gemm_bt<bf16_t><<<dim3(BT / 128, 1), 256, 0, stream>>>(xb, Wkdb, cb, BT, RK, DM);
  // q~ = x @ Wq_eff^T    [8192, 512]
  gemm_bt<bf16_t><<<dim3(BT / 128, QC / 128), 256, 0, stream>>>(xb, Wqe, qtb, BT, QC, DM);
  // cT
  transpose_c<<<dim3(T_ / 64, B_), 256, 0, stream>>>(cb, cTb);
  // attention -> U [8192, 512]
  attn_kernel<<<dim3(T_ / 128, NH, B_), 256, 0, stream>>>(qtb, cb, cTb, Ub);
  // out = U @ W_eff^T    [8192, 1024] f32
  gemm_bt<float><<<dim3(BT / 128, DM / 128), 256, 0, stream>>>(Ub, Wfe, out, BT, DM, QC);
}